// Round 18
// baseline (270.483 us; speedup 1.0000x reference)
//
#include <hip/hip_runtime.h>
#include <hip/hip_bf16.h>

#define M 8192
#define N 8192
#define K 512
#define BMt 128
#define BNt 128
#define BK 32
#define RPAD 136  // ring row stride (bf16): 272B -> bank rotation, 16B aligned

typedef __attribute__((ext_vector_type(8))) short bf16x8;
typedef __attribute__((ext_vector_type(4))) float f32x4;
typedef __attribute__((ext_vector_type(8))) unsigned short us8;

__device__ inline void gload_lds16(const void* g, void* l) {
  __builtin_amdgcn_global_load_lds(
      (const __attribute__((address_space(1))) unsigned int*)g,
      (__attribute__((address_space(3))) unsigned int*)l, 16, 0, 0);
}

#define BARRIER()                          \
  do {                                     \
    asm volatile("" ::: "memory");         \
    __builtin_amdgcn_s_barrier();          \
    asm volatile("" ::: "memory");         \
  } while (0)

#define BARRIER_LGKM()                                 \
  do {                                                 \
    asm volatile("s_waitcnt lgkmcnt(0)" ::: "memory"); \
    __builtin_amdgcn_s_barrier();                      \
    asm volatile("" ::: "memory");                     \
  } while (0)

// Fused prep: cast f32 rows -> bf16, store INVERSE L2 norm (1/max(norm,1e-4)).
__global__ __launch_bounds__(256) void prep_kernel(const float* __restrict__ img,
                                                   const float* __restrict__ txt,
                                                   unsigned short* __restrict__ Abf,
                                                   unsigned short* __restrict__ Bbf,
                                                   float* __restrict__ w1,
                                                   float* __restrict__ w2) {
  const int half = blockIdx.x >> 11;
  const int lb = blockIdx.x & 2047;
  const float* in = half ? txt : img;
  unsigned short* outb = half ? Bbf : Abf;
  float* norms = half ? w2 : w1;

  const int gw = (lb * 256 + threadIdx.x) >> 6;
  const int lane = threadIdx.x & 63;
  const float4* rp4 = (const float4*)(in + (size_t)gw * K);
  float4 v0 = rp4[lane * 2];
  float4 v1 = rp4[lane * 2 + 1];
  float ss = v0.x * v0.x + v0.y * v0.y + v0.z * v0.z + v0.w * v0.w +
             v1.x * v1.x + v1.y * v1.y + v1.z * v1.z + v1.w * v1.w;
  float f[8] = {v0.x, v0.y, v0.z, v0.w, v1.x, v1.y, v1.z, v1.w};
  us8 o;
#pragma unroll
  for (int i = 0; i < 8; ++i) {
    __hip_bfloat16 b = __float2bfloat16(f[i]);
    o[i] = *(unsigned short*)&b;
  }
  *(us8*)(outb + (size_t)gw * K + lane * 8) = o;
#pragma unroll
  for (int off = 32; off > 0; off >>= 1) ss += __shfl_down(ss, off, 64);
  if (lane == 0) norms[gw] = 1.0f / fmaxf(sqrtf(ss), 1e-4f);
}

// Producer-consumer GEMM: 1024 blocks x 320 thr. Waves 0-3 compute (r9
// K-loop, vmcnt queue = LOADS ONLY); wave 4 = writer (queue = STORES ONLY,
// never waits). Block: fixed 128-row strip, 4 col tiles. Tile t's raw acc
// dumps to a bf16 LDS ring at its last step; writer drains it (scaled,
// full-line f32x4 stores) during tile t+1's K-loop. Per-wave vmcnt FIFOs
// mean compute waves never stall behind C-store retirement (r16/r17 bug).
__global__ __launch_bounds__(320, 3) void gemm_kernel(const unsigned short* __restrict__ A,
                                                      const unsigned short* __restrict__ B,
                                                      const float* __restrict__ iw1,
                                                      const float* __restrict__ iw2,
                                                      float* __restrict__ C) {
  __shared__ __align__(16) unsigned short As[2][BMt * BK];   // 2 x 8 KB
  __shared__ __align__(16) unsigned short Bs[3][BNt * BK];   // 3 x 8 KB
  __shared__ __align__(16) unsigned short ring[128 * RPAD];  // 34.8 KB

  const int tid = threadIdx.x;
  const int wave = tid >> 6;  // 0..4
  const int lane = tid & 63;

  const int xcd = blockIdx.x & 7;
  const int idx = blockIdx.x >> 3;          // 0..127
  const int bRow = (idx >> 1) * BMt;        // 64 row strips
  const int cb = xcd * 8 + (idx & 1) * 4;   // 4-panel window in XCD col range

  if (wave < 4) {
    // ================= COMPUTE WAVES =================
    const int wr = wave >> 1, wc = wave & 1;
    const int fr = lane & 15, fq = lane >> 4;
    const int srow = lane >> 2;
    const int scol = (((lane & 3) ^ ((srow >> 1) & 3)) * 8);

    auto stageA = [&](int buf, int sl) {
#pragma unroll
      for (int c = 0; c < 2; ++c)
        gload_lds16(A + (size_t)(bRow + c * 64 + wave * 16 + srow) * K + sl * BK + scol,
                    (char*)&As[buf][0] + (c * 64 + wave * 16) * 64);
    };
    auto stageB = [&](int buf, int bCol, int sl) {
#pragma unroll
      for (int c = 0; c < 2; ++c)
        gload_lds16(B + (size_t)(bCol + c * 64 + wave * 16 + srow) * K + sl * BK + scol,
                    (char*)&Bs[buf][0] + (c * 64 + wave * 16) * 64);
    };
    auto ldA = [&](int buf, int r) -> bf16x8 {
      return *(const bf16x8*)((const char*)&As[buf][0] + r * 64 + ((fq ^ ((r >> 1) & 3)) * 16));
    };
    auto ldB = [&](int buf, int r) -> bf16x8 {
      return *(const bf16x8*)((const char*)&Bs[buf][0] + r * 64 + ((fq ^ ((r >> 1) & 3)) * 16));
    };

    // Prologue: A slice0, B(g=0), B(g=1); A0,B0 landed, B1 in flight.
    stageA(0, 0);
    stageB(0, cb * BNt, 0);
    stageB(1, cb * BNt, 1);
    asm volatile("s_waitcnt vmcnt(2)" ::: "memory");
    BARRIER();

#pragma unroll
    for (int t = 0; t < 4; ++t) {
      f32x4 acc[4][4];
#pragma unroll
      for (int m = 0; m < 4; ++m)
#pragma unroll
        for (int n = 0; n < 4; ++n) acc[m][n] = (f32x4){0.f, 0.f, 0.f, 0.f};

#pragma unroll
      for (int s = 0; s < 16; ++s) {
        const int g = t * 16 + s;
        const int curA = s & 1, nxtA = curA ^ 1;

        stageA(nxtA, (s + 1) & 15);  // A panel identical across tiles
        {
          const int g2 = (g + 2 > 63) ? 63 : (g + 2);  // clamped dummy at tail
          stageB((g + 2) % 3, (cb + (g2 >> 4)) * BNt, g2 & 15);
        }

        bf16x8 a[4], b[4];
#pragma unroll
        for (int m = 0; m < 4; ++m) a[m] = ldA(curA, wr * 64 + m * 16 + fr);
        const int bc = g % 3;
#pragma unroll
        for (int n = 0; n < 4; ++n) b[n] = ldB(bc, wc * 64 + n * 16 + fr);

        __builtin_amdgcn_s_setprio(1);
#pragma unroll
        for (int m = 0; m < 4; ++m)
#pragma unroll
          for (int n = 0; n < 4; ++n)
            acc[m][n] = __builtin_amdgcn_mfma_f32_16x16x32_bf16(a[m], b[n], acc[m][n], 0, 0, 0);
        __builtin_amdgcn_s_setprio(0);

        // Loads-only queue: [B(g+1)x2][A(g+1)x2][B(g+2)x2] -> vmcnt(2).
        asm volatile("s_waitcnt vmcnt(2)" ::: "memory");

        if (s == 15) {
          // Dump raw acc -> ring (bf16). Writer is idle at s==15 (chunk 15
          // drained at s==14), so no read race. Visible after lgkm barrier.
#pragma unroll
          for (int m = 0; m < 4; ++m)
#pragma unroll
            for (int n = 0; n < 4; ++n)
#pragma unroll
              for (int r = 0; r < 4; ++r) {
                __hip_bfloat16 h = __float2bfloat16(acc[m][n][r]);
                ring[(wr * 64 + m * 16 + fq * 4 + r) * RPAD + wc * 64 + n * 16 + fr] =
                    *(unsigned short*)&h;
              }
          BARRIER_LGKM();
        } else {
          BARRIER();
        }
      }
    }
    // compute waves exit; writer drains tile 3 independently.
  } else {
    // ================= WRITER WAVE =================
    const int rsub = lane >> 3;       // 0..7 row-within-chunk
    const int cg = (lane & 7) * 16;   // f32 col group in tile

    // Preload ALL scales -> writer's VMEM queue is pure stores afterwards.
    float i1p[16];
#pragma unroll
    for (int c = 0; c < 16; ++c) i1p[c] = iw1[bRow + c * 8 + rsub];
    f32x4 i2p[4][4];
#pragma unroll
    for (int t = 0; t < 4; ++t)
#pragma unroll
      for (int j = 0; j < 4; ++j)
        i2p[t][j] = *(const f32x4*)&iw2[(cb + t) * BNt + cg + j * 4];

    BARRIER();  // prologue barrier (matches compute)

    auto drain = [&](int dt, int c, const f32x4 (&i2)[4]) {
      const int rrow = c * 8 + rsub;
      us8 h0 = *(const us8*)&ring[rrow * RPAD + cg];
      us8 h1 = *(const us8*)&ring[rrow * RPAD + cg + 8];
      const float i1 = i1p[c];
      float* dst = C + (size_t)(bRow + rrow) * N + (cb + dt) * BNt + cg;
#pragma unroll
      for (int q = 0; q < 4; ++q) {
        f32x4 v;
#pragma unroll
        for (int e = 0; e < 4; ++e) {
          const unsigned short hbits = (q < 2) ? (unsigned short)h0[q * 4 + e]
                                               : (unsigned short)h1[(q - 2) * 4 + e];
          v[e] = __uint_as_float((unsigned)hbits << 16) * i1 * i2[q][e];
        }
        *(f32x4*)(dst + q * 4) = v;
      }
    };

#pragma unroll
    for (int t = 0; t < 4; ++t) {
#pragma unroll
      for (int s = 0; s < 16; ++s) {
        if (t >= 1 && s < 15) {
          if (t == 1) drain(0, s, i2p[0]);
          if (t == 2) drain(1, s, i2p[1]);
          if (t == 3) drain(2, s, i2p[2]);
        }
        if (t >= 1 && s == 14) {  // chunk 15 early so s==15 is race-free
          if (t == 1) drain(0, 15, i2p[0]);
          if (t == 2) drain(1, 15, i2p[1]);
          if (t == 3) drain(2, 15, i2p[2]);
        }
        BARRIER();
      }
    }
    // Tail: drain tile 3 (ring dumped at g=63's lgkm barrier).
#pragma unroll
    for (int c = 0; c < 16; ++c) drain(3, c, i2p[3]);
  }
}

extern "C" void kernel_launch(void* const* d_in, const int* in_sizes, int n_in,
                              void* d_out, int out_size, void* d_ws, size_t ws_size,
                              hipStream_t stream) {
  (void)in_sizes; (void)n_in; (void)out_size; (void)ws_size;
  const float* img = (const float*)d_in[0];
  const float* txt = (const float*)d_in[1];
  float* out = (float*)d_out;

  unsigned short* Abf = (unsigned short*)d_ws;
  unsigned short* Bbf = Abf + (size_t)M * K;
  float* w1 = (float*)(Bbf + (size_t)N * K);
  float* w2 = w1 + M;

  prep_kernel<<<4096, 256, 0, stream>>>(img, txt, Abf, Bbf, w1, w2);
  gemm_kernel<<<1024, 320, 0, stream>>>(Abf, Bbf, w1, w2, out);
}

// Round 19
// 107.574 us; speedup vs baseline: 2.5144x; 2.5144x over previous
//
#include <hip/hip_runtime.h>
#include <hip/hip_bf16.h>

#define M 8192
#define N 8192
#define K 512
#define BM 128
#define BN 128
#define BK 32
#define NT (K / BK)  // 16 K-steps
#define EPAD 132     // epilogue LDS row stride (floats): 528B, 16B-aligned

typedef __attribute__((ext_vector_type(8))) short bf16x8;
typedef __attribute__((ext_vector_type(4))) float f32x4;
typedef __attribute__((ext_vector_type(8))) unsigned short us8;

__device__ inline void gload_lds16(const void* g, void* l) {
  __builtin_amdgcn_global_load_lds(
      (const __attribute__((address_space(1))) unsigned int*)g,
      (__attribute__((address_space(3))) unsigned int*)l, 16, 0, 0);
}

#define BARRIER()                          \
  do {                                     \
    asm volatile("" ::: "memory");         \
    __builtin_amdgcn_s_barrier();          \
    asm volatile("" ::: "memory");         \
  } while (0)

// lgkm-only barrier: LDS ops drained, VMEM (global loads/stores) in flight.
#define BARRIER_LGKM()                                 \
  do {                                                 \
    asm volatile("s_waitcnt lgkmcnt(0)" ::: "memory"); \
    __builtin_amdgcn_s_barrier();                      \
    asm volatile("" ::: "memory");                     \
  } while (0)

// Fused prep: cast f32 rows -> bf16, store INVERSE L2 norm (1/max(norm,1e-4)).
__global__ __launch_bounds__(256) void prep_kernel(const float* __restrict__ img,
                                                   const float* __restrict__ txt,
                                                   unsigned short* __restrict__ Abf,
                                                   unsigned short* __restrict__ Bbf,
                                                   float* __restrict__ w1,
                                                   float* __restrict__ w2) {
  const int half = blockIdx.x >> 11;
  const int lb = blockIdx.x & 2047;
  const float* in = half ? txt : img;
  unsigned short* outb = half ? Bbf : Abf;
  float* norms = half ? w2 : w1;

  const int gw = (lb * 256 + threadIdx.x) >> 6;
  const int lane = threadIdx.x & 63;
  const float4* rp4 = (const float4*)(in + (size_t)gw * K);
  float4 v0 = rp4[lane * 2];
  float4 v1 = rp4[lane * 2 + 1];
  float ss = v0.x * v0.x + v0.y * v0.y + v0.z * v0.z + v0.w * v0.w +
             v1.x * v1.x + v1.y * v1.y + v1.z * v1.z + v1.w * v1.w;
  float f[8] = {v0.x, v0.y, v0.z, v0.w, v1.x, v1.y, v1.z, v1.w};
  us8 o;
#pragma unroll
  for (int i = 0; i < 8; ++i) {
    __hip_bfloat16 b = __float2bfloat16(f[i]);
    o[i] = *(unsigned short*)&b;
  }
  *(us8*)(outb + (size_t)gw * K + lane * 8) = o;
#pragma unroll
  for (int off = 32; off > 0; off >>= 1) ss += __shfl_down(ss, off, 64);
  if (lane == 0) norms[gw] = 1.0f / fmaxf(sqrtf(ss), 1e-4f);
}

// 128x128 bf16 GEMM (r9 K-loop) + full-line LDS-staged epilogue (r13).
// Best verified configuration: 107.49 us total.
__global__ __launch_bounds__(256, 4) void gemm_kernel(const unsigned short* __restrict__ A,
                                                      const unsigned short* __restrict__ B,
                                                      const float* __restrict__ iw1,
                                                      const float* __restrict__ iw2,
                                                      float* __restrict__ C) {
  // 40 KB shared pool: K-loop As[2]/Bs[3] overlaid with epilogue tile (33.8 KB)
  __shared__ __align__(16) char smem[(2 * BM * BK + 3 * BN * BK) * 2];
  auto AsP = [&](int buf) { return (unsigned short*)(smem + buf * BM * BK * 2); };
  auto BsP = [&](int buf) { return (unsigned short*)(smem + 2 * BM * BK * 2 + buf * BN * BK * 2); };
  float* eps = (float*)smem;  // epilogue: 64 rows x EPAD floats

  const int tid = threadIdx.x;
  const int wave = tid >> 6;  // 0..3
  const int lane = tid & 63;
  const int wr = wave >> 1;  // 0..1 : M strip of 64
  const int wc = wave & 1;   // 0..1 : N strip of 64
  const int fr = lane & 15;
  const int fq = lane >> 4;

  // Two-level swizzle: xcd owns col-panels [xcd*8, xcd*8+8).
  const int xcd = blockIdx.x & 7;
  const int idx = blockIdx.x >> 3;              // 0..511
  const int bRow = (idx >> 3) * BM;             // 64 row-panels of 128
  const int bCol = (xcd * 8 + (idx & 7)) * BN;  // 64 col-panels of 128

  // Staging: 16 rows x 64B per wave per call; source granule pre-swizzled
  // so LDS slot jl holds global granule jl ^ ((row>>1)&3)  (rule #21).
  const int srow = lane >> 2;                               // 0..15
  const int scol = (((lane & 3) ^ ((srow >> 1) & 3)) * 8);  // bf16 offset

  auto stageA = [&](int buf, int kt) {
#pragma unroll
    for (int c = 0; c < 2; ++c)
      gload_lds16(A + (size_t)(bRow + c * 64 + wave * 16 + srow) * K + kt * BK + scol,
                  (char*)AsP(buf) + (c * 64 + wave * 16) * 64);
  };
  auto stageB = [&](int buf, int kt) {
#pragma unroll
    for (int c = 0; c < 2; ++c)
      gload_lds16(B + (size_t)(bCol + c * 64 + wave * 16 + srow) * K + kt * BK + scol,
                  (char*)BsP(buf) + (c * 64 + wave * 16) * 64);
  };
  auto ldA = [&](int buf, int r) -> bf16x8 {
    return *(const bf16x8*)((const char*)AsP(buf) + r * 64 + ((fq ^ ((r >> 1) & 3)) * 16));
  };
  auto ldB = [&](int buf, int r) -> bf16x8 {
    return *(const bf16x8*)((const char*)BsP(buf) + r * 64 + ((fq ^ ((r >> 1) & 3)) * 16));
  };

  f32x4 acc[4][4] = {};

  // Prologue: A(0) x2, B(0) x2, B(1) x2 -> need A0,B0 landed, B1 in flight.
  stageA(0, 0);
  stageB(0, 0);
  stageB(1, 1);
  asm volatile("s_waitcnt vmcnt(2)" ::: "memory");
  BARRIER();

#pragma unroll
  for (int t = 0; t < NT; ++t) {
    const int cur = t & 1, nxt = cur ^ 1;
    const int bc = t % 3, b2 = (t + 2) % 3;

    if (t + 1 < NT) stageA(nxt, t + 1);  // 2 gloads
    if (t + 2 < NT) stageB(b2, t + 2);   // 2 gloads

    bf16x8 a[4], b[4];
#pragma unroll
    for (int m = 0; m < 4; ++m) a[m] = ldA(cur, wr * 64 + m * 16 + fr);
#pragma unroll
    for (int n = 0; n < 4; ++n) b[n] = ldB(bc, wc * 64 + n * 16 + fr);

    __builtin_amdgcn_s_setprio(1);
#pragma unroll
    for (int m = 0; m < 4; ++m)
#pragma unroll
      for (int n = 0; n < 4; ++n)
        acc[m][n] = __builtin_amdgcn_mfma_f32_16x16x32_bf16(a[m], b[n], acc[m][n], 0, 0, 0);
    __builtin_amdgcn_s_setprio(0);

    if (t < NT - 2) {
      asm volatile("s_waitcnt vmcnt(2)" ::: "memory");
    } else if (t == NT - 2) {
      asm volatile("s_waitcnt vmcnt(0)" ::: "memory");
    }
    BARRIER();
  }

  // Norm scales. C/D layout: col = lane&15, row = (lane>>4)*4 + reg.
  float i1v[4][4], i2v[4];
#pragma unroll
  for (int m = 0; m < 4; ++m)
#pragma unroll
    for (int r = 0; r < 4; ++r) i1v[m][r] = iw1[bRow + wr * 64 + m * 16 + fq * 4 + r];
#pragma unroll
  for (int n = 0; n < 4; ++n) i2v[n] = iw2[bCol + wc * 64 + n * 16 + fr];

  // Full-line epilogue: two 64-row halves through LDS.
  const int erow = tid >> 5;        // 0..7 (row-within-pass)
  const int ecol = (tid & 31) * 4;  // f32 col (covers 0..127)
#pragma unroll
  for (int h = 0; h < 2; ++h) {
    BARRIER_LGKM();  // h=0: K-loop ds ops done; h=1: prior readout reads done
#pragma unroll
    for (int dm = 0; dm < 2; ++dm) {
      const int m = 2 * h + dm;
#pragma unroll
      for (int n = 0; n < 4; ++n) {
        f32x4 v = acc[m][n];
        const int lc = wc * 64 + n * 16 + fr;
#pragma unroll
        for (int r = 0; r < 4; ++r) {
          const int lr = wr * 32 + dm * 16 + fq * 4 + r;
          eps[lr * EPAD + lc] = v[r] * i1v[m][r] * i2v[n];
        }
      }
    }
    BARRIER_LGKM();
#pragma unroll
    for (int p = 0; p < 8; ++p) {
      const int lr = p * 8 + erow;  // 0..63
      f32x4 v = *(const f32x4*)&eps[lr * EPAD + ecol];
      const int gRow = bRow + (lr >> 5) * 64 + (2 * h + ((lr >> 4) & 1)) * 16 + (lr & 15);
      *(f32x4*)&C[(size_t)gRow * N + bCol + ecol] = v;
    }
  }
}

extern "C" void kernel_launch(void* const* d_in, const int* in_sizes, int n_in,
                              void* d_out, int out_size, void* d_ws, size_t ws_size,
                              hipStream_t stream) {
  (void)in_sizes; (void)n_in; (void)out_size; (void)ws_size;
  const float* img = (const float*)d_in[0];
  const float* txt = (const float*)d_in[1];
  float* out = (float*)d_out;

  unsigned short* Abf = (unsigned short*)d_ws;
  unsigned short* Bbf = Abf + (size_t)M * K;
  float* w1 = (float*)(Bbf + (size_t)N * K);
  float* w2 = w1 + M;

  prep_kernel<<<4096, 256, 0, stream>>>(img, txt, Abf, Bbf, w1, w2);
  gemm_kernel<<<(M / BM) * (N / BN), 256, 0, stream>>>(Abf, Bbf, w1, w2, out);
}